// Round 3
// baseline (2268.217 us; speedup 1.0000x reference)
//
#include <hip/hip_runtime.h>
#include <math.h>

#define N_NODES 200000
#define N_EDGES 6400000
#define F_INF   512
#define HID     16
#define NCLS    7

// ---------------- zero accumulators ----------------
__global__ __launch_bounds__(256) void zero_kernel(float* __restrict__ p, int n4) {
    int i = blockIdx.x * 256 + threadIdx.x;
    if (i < n4) ((float4*)p)[i] = make_float4(0.f, 0.f, 0.f, 0.f);
}

// ---------------- layer 1 GEMM: x[N,512] x (W1[0]|W1[1]|root1)[512,48] ----------------
// hbuf: [N,32] = (h0[16], h1[16]) ; rbuf: [N,16]
__global__ __launch_bounds__(256) void gemm1_kernel(
    const float* __restrict__ x, const float* __restrict__ W1,
    const float* __restrict__ root1,
    float* __restrict__ hbuf, float* __restrict__ rbuf) {
    int row = blockIdx.x * 256 + threadIdx.x;
    if (row >= N_NODES) return;
    const float4* xr = (const float4*)(x + (size_t)row * F_INF);
    float acc0[HID], acc1[HID], accr[HID];
    #pragma unroll
    for (int j = 0; j < HID; ++j) { acc0[j] = 0.f; acc1[j] = 0.f; accr[j] = 0.f; }
    const float* __restrict__ W1b = W1 + F_INF * HID;
    for (int k4 = 0; k4 < F_INF / 4; ++k4) {
        float4 xv = xr[k4];
        #pragma unroll
        for (int kk = 0; kk < 4; ++kk) {
            float xs = (kk == 0) ? xv.x : (kk == 1) ? xv.y : (kk == 2) ? xv.z : xv.w;
            int k = k4 * 4 + kk;
            #pragma unroll
            for (int j = 0; j < HID; ++j) {
                acc0[j] = fmaf(xs, W1 [k * HID + j], acc0[j]);
                acc1[j] = fmaf(xs, W1b[k * HID + j], acc1[j]);
                accr[j] = fmaf(xs, root1[k * HID + j], accr[j]);
            }
        }
    }
    float* hb = hbuf + (size_t)row * 32;
    float* rb = rbuf + (size_t)row * HID;
    #pragma unroll
    for (int j = 0; j < HID; ++j) {
        hb[j]       = acc0[j];
        hb[HID + j] = acc1[j];
        rb[j]       = accr[j];
    }
}

// ---------------- edge pass 1: 4 lanes per edge, 4 channels each ----------------
__global__ __launch_bounds__(256) void edge1_kernel(
    const float* __restrict__ eattr, const int* __restrict__ src,
    const int* __restrict__ dst, const float* __restrict__ hbuf,
    float* __restrict__ agg1, float* __restrict__ deg) {
    int t = blockIdx.x * 256 + threadIdx.x;
    int e = t >> 2;
    if (e >= N_EDGES) return;
    int c4 = (t & 3) << 2;
    float b1 = fminf(fmaxf(eattr[e], 0.f), 1.f);
    float b0 = 1.f - b1;
    int s = src[e], d = dst[e];
    const float4 h0 = *(const float4*)(hbuf + (size_t)s * 32 + c4);
    const float4 h1 = *(const float4*)(hbuf + (size_t)s * 32 + 16 + c4);
    float* a = agg1 + (size_t)d * HID + c4;
    atomicAdd(a + 0, fmaf(h0.x, b0, h1.x * b1));
    atomicAdd(a + 1, fmaf(h0.y, b0, h1.y * b1));
    atomicAdd(a + 2, fmaf(h0.z, b0, h1.z * b1));
    atomicAdd(a + 3, fmaf(h0.w, b0, h1.w * b1));
    if ((t & 3) == 0) atomicAdd(deg + d, 1.0f);
}

// ---------------- node pass 1: elu(agg/deg + r + bias1) -> tiny layer-2 transforms ----------------
// h2buf: [N,16] = (h2_0[7],pad, h2_1[7],pad) ; r2buf: [N,8] = (r2[7],pad)
__global__ __launch_bounds__(256) void node1_kernel(
    const float* __restrict__ agg1, const float* __restrict__ deg,
    const float* __restrict__ rbuf, const float* __restrict__ bias1,
    const float* __restrict__ W2, const float* __restrict__ root2,
    float* __restrict__ h2buf, float* __restrict__ r2buf) {
    int n = blockIdx.x * 256 + threadIdx.x;
    if (n >= N_NODES) return;
    float inv = 1.0f / fmaxf(deg[n], 1.0f);
    float h[HID];
    #pragma unroll
    for (int j = 0; j < HID; ++j) {
        float v = fmaf(agg1[(size_t)n * HID + j], inv, rbuf[(size_t)n * HID + j]) + bias1[j];
        h[j] = v > 0.f ? v : expm1f(v);
    }
    float o0[NCLS], o1[NCLS], orr[NCLS];
    #pragma unroll
    for (int j = 0; j < NCLS; ++j) { o0[j] = 0.f; o1[j] = 0.f; orr[j] = 0.f; }
    const float* __restrict__ W2b = W2 + HID * NCLS;
    #pragma unroll
    for (int k = 0; k < HID; ++k) {
        #pragma unroll
        for (int j = 0; j < NCLS; ++j) {
            o0[j]  = fmaf(h[k], W2 [k * NCLS + j], o0[j]);
            o1[j]  = fmaf(h[k], W2b[k * NCLS + j], o1[j]);
            orr[j] = fmaf(h[k], root2[k * NCLS + j], orr[j]);
        }
    }
    float* hb = h2buf + (size_t)n * 16;
    float* r2 = r2buf + (size_t)n * 8;
    #pragma unroll
    for (int j = 0; j < NCLS; ++j) { hb[j] = o0[j]; hb[8 + j] = o1[j]; r2[j] = orr[j]; }
    hb[7] = 0.f; hb[15] = 0.f; r2[7] = 0.f;
}

// ---------------- edge pass 2: 8 lanes per edge, 1 channel each (7 active) ----------------
__global__ __launch_bounds__(256) void edge2_kernel(
    const float* __restrict__ eattr, const int* __restrict__ src,
    const int* __restrict__ dst, const float* __restrict__ h2buf,
    float* __restrict__ agg2) {
    int t = blockIdx.x * 256 + threadIdx.x;
    int e = t >> 3;
    if (e >= N_EDGES) return;
    int j = t & 7;
    float b1 = fminf(fmaxf(eattr[e], 0.f), 1.f);
    float b0 = 1.f - b1;
    int s = src[e], d = dst[e];
    if (j < NCLS) {
        float m = fmaf(h2buf[(size_t)s * 16 + j], b0, h2buf[(size_t)s * 16 + 8 + j] * b1);
        atomicAdd(agg2 + (size_t)d * 8 + j, m);
    }
}

// ---------------- node pass 2: agg2/deg + r2 + bias2 -> log_softmax ----------------
__global__ __launch_bounds__(256) void node2_kernel(
    const float* __restrict__ agg2, const float* __restrict__ deg,
    const float* __restrict__ r2buf, const float* __restrict__ bias2,
    float* __restrict__ out) {
    int n = blockIdx.x * 256 + threadIdx.x;
    if (n >= N_NODES) return;
    float inv = 1.0f / fmaxf(deg[n], 1.0f);
    float v[NCLS];
    float mx = -INFINITY;
    #pragma unroll
    for (int j = 0; j < NCLS; ++j) {
        v[j] = fmaf(agg2[(size_t)n * 8 + j], inv, r2buf[(size_t)n * 8 + j]) + bias2[j];
        mx = fmaxf(mx, v[j]);
    }
    float sum = 0.f;
    #pragma unroll
    for (int j = 0; j < NCLS; ++j) sum += expf(v[j] - mx);
    float lse = mx + logf(sum);
    #pragma unroll
    for (int j = 0; j < NCLS; ++j) out[(size_t)n * NCLS + j] = v[j] - lse;
}

extern "C" void kernel_launch(void* const* d_in, const int* in_sizes, int n_in,
                              void* d_out, int out_size, void* d_ws, size_t ws_size,
                              hipStream_t stream) {
    const float* x     = (const float*)d_in[0];
    const float* eattr = (const float*)d_in[1];
    const int*   src   = (const int*)d_in[2];
    const int*   dst   = (const int*)d_in[3];
    const float* W1    = (const float*)d_in[4];
    const float* root1 = (const float*)d_in[5];
    const float* bias1 = (const float*)d_in[6];
    const float* W2    = (const float*)d_in[7];
    const float* root2 = (const float*)d_in[8];
    const float* bias2 = (const float*)d_in[9];
    float* out = (float*)d_out;

    // workspace layout (floats)
    float* ws = (float*)d_ws;
    size_t off = 0;
    float* agg1  = ws + off; off += (size_t)N_NODES * HID;   // 3.2M
    float* deg   = ws + off; off += (size_t)N_NODES;         // 0.2M
    float* agg2  = ws + off; off += (size_t)N_NODES * 8;     // 1.6M  (zeroed region ends here: N*25)
    float* hbuf  = ws + off; off += (size_t)N_NODES * 32;    // 6.4M
    float* rbuf  = ws + off; off += (size_t)N_NODES * HID;   // 3.2M
    float* h2buf = ws + off; off += (size_t)N_NODES * 16;    // 3.2M
    float* r2buf = ws + off; off += (size_t)N_NODES * 8;     // 1.6M

    const int zero_n4 = (N_NODES * 25) / 4;   // agg1+deg+agg2 contiguous
    hipLaunchKernelGGL(zero_kernel, dim3((zero_n4 + 255) / 256), dim3(256), 0, stream,
                       agg1, zero_n4);

    const int node_blocks = (N_NODES + 255) / 256;
    hipLaunchKernelGGL(gemm1_kernel, dim3(node_blocks), dim3(256), 0, stream,
                       x, W1, root1, hbuf, rbuf);

    const int e1_blocks = (int)(((size_t)N_EDGES * 4 + 255) / 256);
    hipLaunchKernelGGL(edge1_kernel, dim3(e1_blocks), dim3(256), 0, stream,
                       eattr, src, dst, hbuf, agg1, deg);

    hipLaunchKernelGGL(node1_kernel, dim3(node_blocks), dim3(256), 0, stream,
                       agg1, deg, rbuf, bias1, W2, root2, h2buf, r2buf);

    const int e2_blocks = (int)(((size_t)N_EDGES * 8 + 255) / 256);
    hipLaunchKernelGGL(edge2_kernel, dim3(e2_blocks), dim3(256), 0, stream,
                       eattr, src, dst, h2buf, agg2);

    hipLaunchKernelGGL(node2_kernel, dim3(node_blocks), dim3(256), 0, stream,
                       agg2, deg, r2buf, bias2, out);
}

// Round 4
// 2005.866 us; speedup vs baseline: 1.1308x; 1.1308x over previous
//
#include <hip/hip_runtime.h>
#include <math.h>

#define N_NODES 200000
#define N_EDGES 6400000
#define F_INF   512
#define HID     16
#define NCLS    7

#define SCAN_TILE 1024
#define NBLK ((N_NODES + SCAN_TILE - 1) / SCAN_TILE)   // 196

// ---------------- zero int buffer ----------------
__global__ __launch_bounds__(256) void zero_kernel(int* __restrict__ p, int n4) {
    int i = blockIdx.x * 256 + threadIdx.x;
    if (i < n4) ((int4*)p)[i] = make_int4(0, 0, 0, 0);
}

// ---------------- histogram of dst ----------------
__global__ __launch_bounds__(256) void hist_kernel(const int* __restrict__ dst,
                                                   int* __restrict__ cnt) {
    int e = blockIdx.x * 256 + threadIdx.x;
    if (e < N_EDGES) atomicAdd(&cnt[dst[e]], 1);
}

// ---------------- scan stage 1: per-1024-tile exclusive scan + tile sums ----------------
__global__ __launch_bounds__(256) void scan1_kernel(const int* __restrict__ cnt,
                                                    int* __restrict__ pos,
                                                    int* __restrict__ bsum) {
    __shared__ int wsum[4];
    int tid = threadIdx.x;
    int base = blockIdx.x * SCAN_TILE + tid * 4;
    int v0 = 0, v1 = 0, v2 = 0, v3 = 0;
    if (base < N_NODES) {  // N_NODES % 4 == 0 so full int4 is safe
        int4 q = *(const int4*)(cnt + base);
        v0 = q.x; v1 = q.y; v2 = q.z; v3 = q.w;
    }
    int s = v0 + v1 + v2 + v3;
    int lane = tid & 63, wid = tid >> 6;
    int incl = s;
    #pragma unroll
    for (int o = 1; o < 64; o <<= 1) {
        int t = __shfl_up(incl, o, 64);
        if (lane >= o) incl += t;
    }
    if (lane == 63) wsum[wid] = incl;
    __syncthreads();
    int woff = 0;
    for (int w = 0; w < wid; ++w) woff += wsum[w];
    int excl = woff + incl - s;
    if (base < N_NODES) {
        int4 w;
        w.x = excl; w.y = excl + v0; w.z = excl + v0 + v1; w.w = excl + v0 + v1 + v2;
        *(int4*)(pos + base) = w;
    }
    if (tid == 255) bsum[blockIdx.x] = woff + incl;
}

// ---------------- scan stage 2: exclusive scan of tile sums (NBLK <= 256) ----------------
__global__ __launch_bounds__(256) void scan2_kernel(int* __restrict__ bsum) {
    __shared__ int wsum[4];
    int tid = threadIdx.x;
    int v = (tid < NBLK) ? bsum[tid] : 0;
    int lane = tid & 63, wid = tid >> 6;
    int incl = v;
    #pragma unroll
    for (int o = 1; o < 64; o <<= 1) {
        int t = __shfl_up(incl, o, 64);
        if (lane >= o) incl += t;
    }
    if (lane == 63) wsum[wid] = incl;
    __syncthreads();
    int woff = 0;
    for (int w = 0; w < wid; ++w) woff += wsum[w];
    if (tid < NBLK) bsum[tid] = woff + incl - v;
}

// ---------------- scan stage 3: add tile offsets -> rowptr & pos ----------------
__global__ __launch_bounds__(256) void scan3_kernel(int* __restrict__ pos,
                                                    const int* __restrict__ bsum,
                                                    int* __restrict__ rowptr) {
    int i = blockIdx.x * 256 + threadIdx.x;
    if (i >= N_NODES) return;
    int r = pos[i] + bsum[i >> 10];
    pos[i] = r;
    rowptr[i] = r;
    if (i == 0) rowptr[N_NODES] = N_EDGES;
}

// ---------------- scatter edge ids into CSR order ----------------
__global__ __launch_bounds__(256) void scatter_kernel(const int* __restrict__ dst,
                                                      int* __restrict__ pos,
                                                      int* __restrict__ sorted_e) {
    int e = blockIdx.x * 256 + threadIdx.x;
    if (e >= N_EDGES) return;
    int p = atomicAdd(&pos[dst[e]], 1);
    sorted_e[p] = e;
}

// ---------------- layer 1 GEMM: x[N,512] x (W1[0]|W1[1]|root1)[512,48] ----------------
__global__ __launch_bounds__(256) void gemm1_kernel(
    const float* __restrict__ x, const float* __restrict__ W1,
    const float* __restrict__ root1,
    float* __restrict__ hbuf, float* __restrict__ rbuf) {
    int row = blockIdx.x * 256 + threadIdx.x;
    if (row >= N_NODES) return;
    const float4* xr = (const float4*)(x + (size_t)row * F_INF);
    float acc0[HID], acc1[HID], accr[HID];
    #pragma unroll
    for (int j = 0; j < HID; ++j) { acc0[j] = 0.f; acc1[j] = 0.f; accr[j] = 0.f; }
    const float* __restrict__ W1b = W1 + F_INF * HID;
    for (int k4 = 0; k4 < F_INF / 4; ++k4) {
        float4 xv = xr[k4];
        #pragma unroll
        for (int kk = 0; kk < 4; ++kk) {
            float xs = (kk == 0) ? xv.x : (kk == 1) ? xv.y : (kk == 2) ? xv.z : xv.w;
            int k = k4 * 4 + kk;
            #pragma unroll
            for (int j = 0; j < HID; ++j) {
                acc0[j] = fmaf(xs, W1 [k * HID + j], acc0[j]);
                acc1[j] = fmaf(xs, W1b[k * HID + j], acc1[j]);
                accr[j] = fmaf(xs, root1[k * HID + j], accr[j]);
            }
        }
    }
    float* hb = hbuf + (size_t)row * 32;
    float* rb = rbuf + (size_t)row * HID;
    #pragma unroll
    for (int j = 0; j < HID; ++j) {
        hb[j]       = acc0[j];
        hb[HID + j] = acc1[j];
        rb[j]       = accr[j];
    }
}

// ---------------- layer-1 gather-aggregate + ELU (16 lanes per node, lane = channel) ----
// rbuf in: root1 contribution; out: h = elu(agg/deg + root + bias1)
__global__ __launch_bounds__(256) void agg1_kernel(
    const int* __restrict__ sorted_e, const int* __restrict__ rowptr,
    const int* __restrict__ srcArr, const float* __restrict__ eattr,
    const float* __restrict__ hbuf, float* rbuf, const float* __restrict__ bias1) {
    int t = blockIdx.x * 256 + threadIdx.x;
    int n = t >> 4;
    if (n >= N_NODES) return;
    int c = t & 15;
    int beg = rowptr[n], end = rowptr[n + 1];
    float acc = 0.f;
    for (int p = beg; p < end; ++p) {
        int e = sorted_e[p];
        int s = srcArr[e];
        float b1 = fminf(fmaxf(eattr[e], 0.f), 1.f);
        float h0 = hbuf[(size_t)s * 32 + c];
        float h1 = hbuf[(size_t)s * 32 + 16 + c];
        acc += fmaf(b1, h1 - h0, h0);   // b0*h0 + b1*h1
    }
    float invd = 1.0f / fmaxf((float)(end - beg), 1.0f);
    float v = fmaf(acc, invd, rbuf[(size_t)n * HID + c]) + bias1[c];
    rbuf[(size_t)n * HID + c] = v > 0.f ? v : expm1f(v);
}

// ---------------- tiny layer-2 transforms (thread per node) ----------------
// h in rbuf[N,16]; h2buf: [N,16] = (h2_0[7],0, h2_1[7],0) ; r2buf: [N,8] = (r2[7],0)
__global__ __launch_bounds__(256) void node1b_kernel(
    const float* __restrict__ hsrc, const float* __restrict__ W2,
    const float* __restrict__ root2,
    float* __restrict__ h2buf, float* __restrict__ r2buf) {
    int n = blockIdx.x * 256 + threadIdx.x;
    if (n >= N_NODES) return;
    float h[HID];
    const float4* hp = (const float4*)(hsrc + (size_t)n * HID);
    #pragma unroll
    for (int q = 0; q < 4; ++q) {
        float4 hv = hp[q];
        h[q * 4 + 0] = hv.x; h[q * 4 + 1] = hv.y; h[q * 4 + 2] = hv.z; h[q * 4 + 3] = hv.w;
    }
    float o0[NCLS], o1[NCLS], orr[NCLS];
    #pragma unroll
    for (int j = 0; j < NCLS; ++j) { o0[j] = 0.f; o1[j] = 0.f; orr[j] = 0.f; }
    const float* __restrict__ W2b = W2 + HID * NCLS;
    #pragma unroll
    for (int k = 0; k < HID; ++k) {
        #pragma unroll
        for (int j = 0; j < NCLS; ++j) {
            o0[j]  = fmaf(h[k], W2 [k * NCLS + j], o0[j]);
            o1[j]  = fmaf(h[k], W2b[k * NCLS + j], o1[j]);
            orr[j] = fmaf(h[k], root2[k * NCLS + j], orr[j]);
        }
    }
    float* hb = h2buf + (size_t)n * 16;
    float* r2 = r2buf + (size_t)n * 8;
    #pragma unroll
    for (int j = 0; j < NCLS; ++j) { hb[j] = o0[j]; hb[8 + j] = o1[j]; r2[j] = orr[j]; }
    hb[7] = 0.f; hb[15] = 0.f; r2[7] = 0.f;
}

// ---------------- layer-2 gather-aggregate + log_softmax (8 lanes per node) ----------
__global__ __launch_bounds__(256) void agg2_kernel(
    const int* __restrict__ sorted_e, const int* __restrict__ rowptr,
    const int* __restrict__ srcArr, const float* __restrict__ eattr,
    const float* __restrict__ h2buf, const float* __restrict__ r2buf,
    const float* __restrict__ bias2, float* __restrict__ out) {
    int t = blockIdx.x * 256 + threadIdx.x;
    int n = t >> 3;
    if (n >= N_NODES) return;
    int j = t & 7;
    int beg = rowptr[n], end = rowptr[n + 1];
    float acc = 0.f;
    for (int p = beg; p < end; ++p) {
        int e = sorted_e[p];
        int s = srcArr[e];
        float b1 = fminf(fmaxf(eattr[e], 0.f), 1.f);
        float m0 = h2buf[(size_t)s * 16 + j];        // lane 7 reads pad = 0
        float m1 = h2buf[(size_t)s * 16 + 8 + j];
        acc += fmaf(b1, m1 - m0, m0);
    }
    float invd = 1.0f / fmaxf((float)(end - beg), 1.0f);
    float v = fmaf(acc, invd, r2buf[(size_t)n * 8 + j]) + ((j < NCLS) ? bias2[j] : 0.f);
    if (j == NCLS) v = -INFINITY;                     // j==7 lane inactive
    float mx = v;
    mx = fmaxf(mx, __shfl_xor(mx, 1, 8));
    mx = fmaxf(mx, __shfl_xor(mx, 2, 8));
    mx = fmaxf(mx, __shfl_xor(mx, 4, 8));
    float ex = expf(v - mx);                          // lane 7: expf(-inf)=0
    float sm = ex;
    sm += __shfl_xor(sm, 1, 8);
    sm += __shfl_xor(sm, 2, 8);
    sm += __shfl_xor(sm, 4, 8);
    float lse = mx + logf(sm);
    if (j < NCLS) out[(size_t)n * NCLS + j] = v - lse;
}

extern "C" void kernel_launch(void* const* d_in, const int* in_sizes, int n_in,
                              void* d_out, int out_size, void* d_ws, size_t ws_size,
                              hipStream_t stream) {
    const float* x     = (const float*)d_in[0];
    const float* eattr = (const float*)d_in[1];
    const int*   src   = (const int*)d_in[2];
    const int*   dst   = (const int*)d_in[3];
    const float* W1    = (const float*)d_in[4];
    const float* root1 = (const float*)d_in[5];
    const float* bias1 = (const float*)d_in[6];
    const float* W2    = (const float*)d_in[7];
    const float* root2 = (const float*)d_in[8];
    const float* bias2 = (const float*)d_in[9];
    float* out = (float*)d_out;

    // workspace layout (4-byte units), ~66.4 MB total
    int* wsI = (int*)d_ws;
    int* cnt      = wsI;                       // 200000
    int* pos      = cnt + N_NODES;             // 200000
    int* rowptr   = pos + N_NODES;             // 200001 (reserve 200004)
    int* bsum     = rowptr + (N_NODES + 4);    // 256
    int* sorted_e = bsum + 256;                // 6.4M
    float* hbuf   = (float*)(sorted_e + N_EDGES);  // 6.4M floats [N,32]
    float* rbuf   = hbuf + (size_t)N_NODES * 32;   // 3.2M floats [N,16]
    // aliases (hbuf dead after agg1):
    float* h2buf  = hbuf;                      // [N,16]
    float* r2buf  = hbuf + (size_t)N_NODES * 16;   // [N,8]

    const int eblocks = (N_EDGES + 255) / 256;       // 25000
    const int nthreads_blocks = (N_NODES + 255) / 256; // 782

    hipLaunchKernelGGL(zero_kernel, dim3((N_NODES / 4 + 255) / 256), dim3(256), 0, stream,
                       cnt, N_NODES / 4);
    hipLaunchKernelGGL(gemm1_kernel, dim3(nthreads_blocks), dim3(256), 0, stream,
                       x, W1, root1, hbuf, rbuf);
    hipLaunchKernelGGL(hist_kernel, dim3(eblocks), dim3(256), 0, stream, dst, cnt);
    hipLaunchKernelGGL(scan1_kernel, dim3(NBLK), dim3(256), 0, stream, cnt, pos, bsum);
    hipLaunchKernelGGL(scan2_kernel, dim3(1), dim3(256), 0, stream, bsum);
    hipLaunchKernelGGL(scan3_kernel, dim3(nthreads_blocks), dim3(256), 0, stream,
                       pos, bsum, rowptr);
    hipLaunchKernelGGL(scatter_kernel, dim3(eblocks), dim3(256), 0, stream,
                       dst, pos, sorted_e);
    hipLaunchKernelGGL(agg1_kernel, dim3((N_NODES * 16 + 255) / 256), dim3(256), 0, stream,
                       sorted_e, rowptr, src, eattr, hbuf, rbuf, bias1);
    hipLaunchKernelGGL(node1b_kernel, dim3(nthreads_blocks), dim3(256), 0, stream,
                       rbuf, W2, root2, h2buf, r2buf);
    hipLaunchKernelGGL(agg2_kernel, dim3((N_NODES * 8 + 255) / 256), dim3(256), 0, stream,
                       sorted_e, rowptr, src, eattr, h2buf, r2buf, bias2, out);
}

// Round 5
// 1071.071 us; speedup vs baseline: 2.1177x; 1.8728x over previous
//
#include <hip/hip_runtime.h>
#include <hip/hip_fp16.h>
#include <math.h>

#define N_NODES 200000
#define N_EDGES 6400000
#define F_INF   512
#define HID     16
#define NCLS    7

#define NPB      256                               // nodes per bucket
#define NBUCKET  ((N_NODES + NPB - 1) / NPB)       // 782
#define CHUNK    16384
#define NBLKE    ((N_EDGES + CHUNK - 1) / CHUNK)   // 391
#define STAGE_CAP 9216                             // mean 8192, sigma~90 -> 11 sigma headroom

// ======================= layer 1 GEMM =======================
// x[N,512] x (W1[0]|W1[1]|root1)[512,48]
// hbufH[n*16+c] = half2(h0_c, h1_c) ; rbufH[n*16+c] = half(root contribution)
__global__ __launch_bounds__(256) void gemm1_kernel(
    const float* __restrict__ x, const float* __restrict__ W1,
    const float* __restrict__ root1,
    __half2* __restrict__ hbufH, __half* __restrict__ rbufH) {
    int row = blockIdx.x * 256 + threadIdx.x;
    if (row >= N_NODES) return;
    const float4* xr = (const float4*)(x + (size_t)row * F_INF);
    float acc0[HID], acc1[HID], accr[HID];
    #pragma unroll
    for (int j = 0; j < HID; ++j) { acc0[j] = 0.f; acc1[j] = 0.f; accr[j] = 0.f; }
    const float* __restrict__ W1b = W1 + F_INF * HID;
    for (int k4 = 0; k4 < F_INF / 4; ++k4) {
        float4 xv = xr[k4];
        #pragma unroll
        for (int kk = 0; kk < 4; ++kk) {
            float xs = (kk == 0) ? xv.x : (kk == 1) ? xv.y : (kk == 2) ? xv.z : xv.w;
            int k = k4 * 4 + kk;
            #pragma unroll
            for (int j = 0; j < HID; ++j) {
                acc0[j] = fmaf(xs, W1 [k * HID + j], acc0[j]);
                acc1[j] = fmaf(xs, W1b[k * HID + j], acc1[j]);
                accr[j] = fmaf(xs, root1[k * HID + j], accr[j]);
            }
        }
    }
    __half2* hb = hbufH + (size_t)row * HID;
    __half*  rb = rbufH + (size_t)row * HID;
    #pragma unroll
    for (int j = 0; j < HID; ++j) {
        hb[j] = __floats2half2_rn(acc0[j], acc1[j]);
        rb[j] = __float2half(accr[j]);
    }
}

// ======================= P1: per-block bucket histogram =======================
__global__ __launch_bounds__(256) void p1_bincount(const int* __restrict__ dst,
                                                   int* __restrict__ blockOff) {
    __shared__ int hist[NBUCKET];
    int tid = threadIdx.x;
    for (int i = tid; i < NBUCKET; i += 256) hist[i] = 0;
    __syncthreads();
    size_t base = (size_t)blockIdx.x * CHUNK;
    for (int i = 0; i < CHUNK / 256; ++i) {
        size_t e = base + (size_t)i * 256 + tid;
        if (e < N_EDGES) atomicAdd(&hist[dst[e] >> 8], 1);
    }
    __syncthreads();
    for (int i = tid; i < NBUCKET; i += 256)
        blockOff[(size_t)i * NBLKE + blockIdx.x] = hist[i];
}

// ======================= P2a: per-bucket scan over blocks =======================
// blockOff row (NBLKE=391 vals) -> exclusive scan in place; bucketTotal[b] = row sum
__global__ __launch_bounds__(256) void p2a_kernel(int* __restrict__ blockOff,
                                                  int* __restrict__ bucketTotal) {
    __shared__ int wsum[4];
    int b = blockIdx.x, tid = threadIdx.x;
    size_t rowb = (size_t)b * NBLKE;
    int i0 = tid * 2, i1 = i0 + 1;
    int v0 = (i0 < NBLKE) ? blockOff[rowb + i0] : 0;
    int v1 = (i1 < NBLKE) ? blockOff[rowb + i1] : 0;
    int s = v0 + v1;
    int lane = tid & 63, wid = tid >> 6;
    int incl = s;
    #pragma unroll
    for (int o = 1; o < 64; o <<= 1) {
        int t = __shfl_up(incl, o, 64);
        if (lane >= o) incl += t;
    }
    if (lane == 63) wsum[wid] = incl;
    __syncthreads();
    int woff = 0;
    for (int w = 0; w < wid; ++w) woff += wsum[w];
    int excl = woff + incl - s;
    if (i0 < NBLKE) blockOff[rowb + i0] = excl;
    if (i1 < NBLKE) blockOff[rowb + i1] = excl + v0;
    if (tid == 255) bucketTotal[b] = woff + incl;
}

// ======================= P2b: scan bucket totals -> bucketStart =======================
__global__ __launch_bounds__(256) void p2b_kernel(const int* __restrict__ bucketTotal,
                                                  int* __restrict__ bucketStart,
                                                  int* __restrict__ rowptr) {
    __shared__ int wsum[4];
    int tid = threadIdx.x;
    int base = tid * 4;
    int v[4]; int s = 0;
    #pragma unroll
    for (int q = 0; q < 4; ++q) {
        int idx = base + q;
        v[q] = (idx < NBUCKET) ? bucketTotal[idx] : 0;
        s += v[q];
    }
    int lane = tid & 63, wid = tid >> 6;
    int incl = s;
    #pragma unroll
    for (int o = 1; o < 64; o <<= 1) {
        int t = __shfl_up(incl, o, 64);
        if (lane >= o) incl += t;
    }
    if (lane == 63) wsum[wid] = incl;
    __syncthreads();
    int woff = 0;
    for (int w = 0; w < wid; ++w) woff += wsum[w];
    int run = woff + incl - s;
    #pragma unroll
    for (int q = 0; q < 4; ++q) {
        int idx = base + q;
        if (idx < NBUCKET) bucketStart[idx] = run;
        run += v[q];
    }
    if (tid == 0) rowptr[N_NODES] = N_EDGES;
}

// ======================= P3: binned scatter of payload =======================
// payload: metaArr[slot] = (local<<18)|src ; wHarr[slot] = half(clip(eattr))
__global__ __launch_bounds__(256) void p3_binscatter(
    const int* __restrict__ dst, const int* __restrict__ src,
    const float* __restrict__ eattr,
    const int* __restrict__ blockOff, const int* __restrict__ bucketStart,
    unsigned int* __restrict__ metaArr, __half* __restrict__ wHarr) {
    __shared__ int cur[NBUCKET];
    int tid = threadIdx.x;
    for (int i = tid; i < NBUCKET; i += 256)
        cur[i] = bucketStart[i] + blockOff[(size_t)i * NBLKE + blockIdx.x];
    __syncthreads();
    size_t base = (size_t)blockIdx.x * CHUNK;
    for (int i = 0; i < CHUNK / 256; ++i) {
        size_t e = base + (size_t)i * 256 + tid;
        if (e < N_EDGES) {
            int d = dst[e];
            int b = d >> 8;
            int slot = atomicAdd(&cur[b], 1);
            unsigned int meta = ((unsigned int)(d & 255) << 18) | (unsigned int)src[e];
            float w = fminf(fmaxf(eattr[e], 0.f), 1.f);
            metaArr[slot] = meta;
            wHarr[slot] = __float2half(w);
        }
    }
}

// ======================= P4: per-bucket fine sort -> CSR + rowptr =======================
__global__ __launch_bounds__(256) void p4_buildcsr(
    const int* __restrict__ bucketStart, const int* __restrict__ bucketTotal,
    unsigned int* __restrict__ metaArr, __half* __restrict__ wHarr,
    int* __restrict__ rowptr) {
    __shared__ unsigned int stageM[STAGE_CAP];
    __shared__ __half stageW[STAGE_CAP];
    __shared__ int hist[NPB];
    __shared__ int wsum[4];
    int b = blockIdx.x, tid = threadIdx.x;
    int start = bucketStart[b];
    int count = bucketTotal[b];
    int nn = min(NPB, N_NODES - b * NPB);
    hist[tid] = 0;
    __syncthreads();
    for (int i = tid; i < count; i += 256) {
        unsigned int m = metaArr[start + i];
        stageM[i] = m;
        stageW[i] = wHarr[start + i];
        atomicAdd(&hist[m >> 18], 1);
    }
    __syncthreads();
    // exclusive scan of hist[256], one element per thread
    int v = hist[tid];
    int lane = tid & 63, wid = tid >> 6;
    int incl = v;
    #pragma unroll
    for (int o = 1; o < 64; o <<= 1) {
        int t = __shfl_up(incl, o, 64);
        if (lane >= o) incl += t;
    }
    if (lane == 63) wsum[wid] = incl;
    __syncthreads();
    int woff = 0;
    for (int w = 0; w < wid; ++w) woff += wsum[w];
    int excl = woff + incl - v;
    if (tid < nn) rowptr[b * NPB + tid] = start + excl;
    __syncthreads();
    hist[tid] = excl;       // becomes the placement cursor
    __syncthreads();
    for (int i = tid; i < count; i += 256) {
        unsigned int m = stageM[i];
        int local = (int)(m >> 18);
        int pos = start + atomicAdd(&hist[local], 1);
        metaArr[pos] = m & 0x3FFFFu;    // plain src id
        wHarr[pos] = stageW[i];
    }
}

// ======================= agg1: gather-aggregate + ELU (16 lanes/node) =======================
__global__ __launch_bounds__(256) void agg1_kernel(
    const unsigned int* __restrict__ metaArr, const __half* __restrict__ wHarr,
    const int* __restrict__ rowptr, const __half2* __restrict__ hbufH,
    __half* __restrict__ rbufH, const float* __restrict__ bias1) {
    int t = blockIdx.x * 256 + threadIdx.x;
    int n = t >> 4;
    if (n >= N_NODES) return;
    int c = t & 15;
    int beg = rowptr[n], end = rowptr[n + 1];
    float acc = 0.f;
    for (int p = beg; p < end; ++p) {
        int s = (int)metaArr[p];
        float b1 = __half2float(wHarr[p]);
        float2 h = __half22float2(hbufH[(size_t)s * HID + c]);
        acc += fmaf(b1, h.y - h.x, h.x);     // b0*h0 + b1*h1
    }
    float invd = 1.0f / fmaxf((float)(end - beg), 1.0f);
    float r = __half2float(rbufH[(size_t)n * HID + c]);
    float vv = fmaf(acc, invd, r) + bias1[c];
    float hv = vv > 0.f ? vv : expm1f(vv);
    rbufH[(size_t)n * HID + c] = __float2half(hv);
}

// ======================= node1b: tiny layer-2 transforms =======================
// h2buf[n*8+j] = half2(o0_j, o1_j), j<7 (j=7 zero) ; r2buf[n*8+j] f32
__global__ __launch_bounds__(256) void node1b_kernel(
    const __half* __restrict__ rbufH, const float* __restrict__ W2,
    const float* __restrict__ root2,
    __half2* __restrict__ h2buf, float* __restrict__ r2buf) {
    int n = blockIdx.x * 256 + threadIdx.x;
    if (n >= N_NODES) return;
    float h[HID];
    #pragma unroll
    for (int k = 0; k < HID; ++k) h[k] = __half2float(rbufH[(size_t)n * HID + k]);
    float o0[NCLS], o1[NCLS], orr[NCLS];
    #pragma unroll
    for (int j = 0; j < NCLS; ++j) { o0[j] = 0.f; o1[j] = 0.f; orr[j] = 0.f; }
    const float* __restrict__ W2b = W2 + HID * NCLS;
    #pragma unroll
    for (int k = 0; k < HID; ++k) {
        #pragma unroll
        for (int j = 0; j < NCLS; ++j) {
            o0[j]  = fmaf(h[k], W2 [k * NCLS + j], o0[j]);
            o1[j]  = fmaf(h[k], W2b[k * NCLS + j], o1[j]);
            orr[j] = fmaf(h[k], root2[k * NCLS + j], orr[j]);
        }
    }
    __half2* hb = h2buf + (size_t)n * 8;
    float*   r2 = r2buf + (size_t)n * 8;
    #pragma unroll
    for (int j = 0; j < NCLS; ++j) {
        hb[j] = __floats2half2_rn(o0[j], o1[j]);
        r2[j] = orr[j];
    }
    hb[7] = __floats2half2_rn(0.f, 0.f);
    r2[7] = 0.f;
}

// ======================= agg2: gather-aggregate + log_softmax (8 lanes/node) ==========
__global__ __launch_bounds__(256) void agg2_kernel(
    const unsigned int* __restrict__ metaArr, const __half* __restrict__ wHarr,
    const int* __restrict__ rowptr, const __half2* __restrict__ h2buf,
    const float* __restrict__ r2buf, const float* __restrict__ bias2,
    float* __restrict__ out) {
    int t = blockIdx.x * 256 + threadIdx.x;
    int n = t >> 3;
    if (n >= N_NODES) return;
    int j = t & 7;
    int beg = rowptr[n], end = rowptr[n + 1];
    float acc = 0.f;
    for (int p = beg; p < end; ++p) {
        int s = (int)metaArr[p];
        float b1 = __half2float(wHarr[p]);
        float2 m = __half22float2(h2buf[(size_t)s * 8 + j]);   // j=7 reads (0,0)
        acc += fmaf(b1, m.y - m.x, m.x);
    }
    float invd = 1.0f / fmaxf((float)(end - beg), 1.0f);
    float v = fmaf(acc, invd, r2buf[(size_t)n * 8 + j]) + ((j < NCLS) ? bias2[j] : 0.f);
    if (j == NCLS) v = -INFINITY;
    float mx = v;
    mx = fmaxf(mx, __shfl_xor(mx, 1, 8));
    mx = fmaxf(mx, __shfl_xor(mx, 2, 8));
    mx = fmaxf(mx, __shfl_xor(mx, 4, 8));
    float ex = expf(v - mx);
    float sm = ex;
    sm += __shfl_xor(sm, 1, 8);
    sm += __shfl_xor(sm, 2, 8);
    sm += __shfl_xor(sm, 4, 8);
    float lse = mx + logf(sm);
    if (j < NCLS) out[(size_t)n * NCLS + j] = v - lse;
}

extern "C" void kernel_launch(void* const* d_in, const int* in_sizes, int n_in,
                              void* d_out, int out_size, void* d_ws, size_t ws_size,
                              hipStream_t stream) {
    const float* x     = (const float*)d_in[0];
    const float* eattr = (const float*)d_in[1];
    const int*   src   = (const int*)d_in[2];
    const int*   dst   = (const int*)d_in[3];
    const float* W1    = (const float*)d_in[4];
    const float* root1 = (const float*)d_in[5];
    const float* bias1 = (const float*)d_in[6];
    const float* W2    = (const float*)d_in[7];
    const float* root2 = (const float*)d_in[8];
    const float* bias2 = (const float*)d_in[9];
    float* out = (float*)d_out;

    // ---------- workspace layout (~60 MB) ----------
    char* wp = (char*)d_ws;
    unsigned int* metaArr = (unsigned int*)wp;  wp += (size_t)N_EDGES * 4;           // 25.6 MB
    __half*       wHarr   = (__half*)wp;        wp += (size_t)N_EDGES * 2;           // 12.8 MB
    int* blockOff    = (int*)wp;                wp += (size_t)NBUCKET * NBLKE * 4;   // 1.22 MB
    int* bucketTotal = (int*)wp;                wp += 1024 * 4;
    int* bucketStart = (int*)wp;                wp += 1024 * 4;
    int* rowptr      = (int*)wp;                wp += (size_t)(N_NODES + 4) * 4;     // 0.8 MB
    __half2* hbufH   = (__half2*)wp;            wp += (size_t)N_NODES * HID * 4;     // 12.8 MB
    __half*  rbufH   = (__half*)wp;             wp += (size_t)N_NODES * HID * 2;     // 6.4 MB
    // aliases: hbufH region is dead after agg1
    __half2* h2buf = hbufH;                                          // N*8 half2 = 6.4 MB
    float*   r2buf = (float*)(hbufH + (size_t)N_NODES * 8);          // N*8 f32   = 6.4 MB

    const int node_blocks = (N_NODES + 255) / 256;  // 782

    hipLaunchKernelGGL(gemm1_kernel, dim3(node_blocks), dim3(256), 0, stream,
                       x, W1, root1, hbufH, rbufH);
    hipLaunchKernelGGL(p1_bincount, dim3(NBLKE), dim3(256), 0, stream, dst, blockOff);
    hipLaunchKernelGGL(p2a_kernel, dim3(NBUCKET), dim3(256), 0, stream,
                       blockOff, bucketTotal);
    hipLaunchKernelGGL(p2b_kernel, dim3(1), dim3(256), 0, stream,
                       bucketTotal, bucketStart, rowptr);
    hipLaunchKernelGGL(p3_binscatter, dim3(NBLKE), dim3(256), 0, stream,
                       dst, src, eattr, blockOff, bucketStart, metaArr, wHarr);
    hipLaunchKernelGGL(p4_buildcsr, dim3(NBUCKET), dim3(256), 0, stream,
                       bucketStart, bucketTotal, metaArr, wHarr, rowptr);
    hipLaunchKernelGGL(agg1_kernel, dim3((N_NODES * 16 + 255) / 256), dim3(256), 0, stream,
                       metaArr, wHarr, rowptr, hbufH, rbufH, bias1);
    hipLaunchKernelGGL(node1b_kernel, dim3(node_blocks), dim3(256), 0, stream,
                       rbufH, W2, root2, h2buf, r2buf);
    hipLaunchKernelGGL(agg2_kernel, dim3((N_NODES * 8 + 255) / 256), dim3(256), 0, stream,
                       metaArr, wHarr, rowptr, h2buf, r2buf, bias2, out);
}